// Round 4
// baseline (417.373 us; speedup 1.0000x reference)
//
#include <hip/hip_runtime.h>

#define EPROJS 1024
#define DUNITS 1024
#define AHEADS 4
#define DK 512
#define DV 512
#define CCH 128
#define BB 16
#define TT 2048

typedef __attribute__((ext_vector_type(8))) short bf16x8;
typedef __attribute__((ext_vector_type(4))) float f32x4;

static __device__ __forceinline__ short f2bf(float x) {
  unsigned u = __float_as_uint(x);
  unsigned r = u + 0x7fffu + ((u >> 16) & 1u);   // RNE to bf16 (inputs finite)
  return (short)(r >> 16);
}
static __device__ __forceinline__ float bf2f(short x) {
  return __uint_as_float(((unsigned)(unsigned short)x) << 16);
}

static __device__ __forceinline__ float fast_tanh(float x) {
  float e2 = __expf(2.0f * x);
  return 1.0f - 2.0f / (e2 + 1.0f);
}

// ---------- f32 -> bf16 conversion (vector of 4) ----------
__global__ __launch_bounds__(256) void cvt_kernel(const float* __restrict__ in,
                                                  short* __restrict__ out, int n4) {
  int i = blockIdx.x * blockDim.x + threadIdx.x;
  if (i >= n4) return;
  float4 v = reinterpret_cast<const float4*>(in)[i];
  short4 o;
  o.x = f2bf(v.x); o.y = f2bf(v.y); o.z = f2bf(v.z); o.w = f2bf(v.w);
  reinterpret_cast<short4*>(out)[i] = o;
}

// ---------- pack B = [Wk | Watt] into MFMA fragment order ----------
// Bp[h][kkidx(36)][nblk(32)][lane(64)][8]; kkidx<32 -> Wk (k=kkidx*32), else Watt.
__global__ __launch_bounds__(256) void packB_kernel(const float* __restrict__ Wk,
                                                    const float* __restrict__ Watt,
                                                    short* __restrict__ Bp) {
  int idx = blockIdx.x * 256 + threadIdx.x;          // 4*36*32*64 = 294912
  if (idx >= 294912) return;
  int lane = idx & 63; int t = idx >> 6;
  int nblk = t & 31; t >>= 5;
  int kkidx = t % 36; int h = t / 36;
  int col = nblk * 16 + (lane & 15);
  int k0 = kkidx * 32 + (lane >> 4) * 8;
  const float* src;
  if (k0 < 1024) src = Wk + ((size_t)(h * DK + col)) * EPROJS + k0;
  else           src = Watt + ((size_t)(h * DK + col)) * CCH + (k0 - 1024);
  float4 v0 = reinterpret_cast<const float4*>(src)[0];
  float4 v1 = reinterpret_cast<const float4*>(src)[1];
  short o[8] = { f2bf(v0.x), f2bf(v0.y), f2bf(v0.z), f2bf(v0.w),
                 f2bf(v1.x), f2bf(v1.y), f2bf(v1.z), f2bf(v1.w) };
  *reinterpret_cast<bf16x8*>(Bp + (size_t)idx * 8) = *reinterpret_cast<bf16x8*>(o);
}

// ---------- filter prefix sums: S[h][tau][c], tau in [0, L] ----------
__global__ __launch_bounds__(128) void prefix_kernel(const float* __restrict__ w0,
                                                     const float* __restrict__ w1,
                                                     const float* __restrict__ w2,
                                                     const float* __restrict__ w3,
                                                     float* __restrict__ S) {
  int h = blockIdx.x, c = threadIdx.x;
  const float* wk = (h == 0) ? w0 : (h == 1) ? w1 : (h == 2) ? w2 : w3;
  int af = (100 * (h + 1)) >> 2;
  int L = 2 * af + 1;
  float* Sh = S + h * 202 * 128;
  float s = 0.f;
  Sh[c] = 0.f;
  for (int t = 0; t < L; ++t) { s += wk[c * L + t]; Sh[(t + 1) * 128 + c] = s; }
}

// ---------- Q[h][b][k] ----------
__global__ __launch_bounds__(256) void q_kernel(const float* __restrict__ dec,
                                                const float* __restrict__ Wq,
                                                const float* __restrict__ bq,
                                                float* __restrict__ Qb) {
  int wid = (blockIdx.x * blockDim.x + threadIdx.x) >> 6;
  int lane = threadIdx.x & 63;
  int k = wid & (DK - 1); int hb = wid >> 9; int b = hb & (BB - 1); int h = hb >> 4;
  const float4* d4 = reinterpret_cast<const float4*>(dec + b * DUNITS);
  const float4* w4 = reinterpret_cast<const float4*>(Wq + (size_t)(h * DK + k) * DUNITS);
  float s = 0.f;
#pragma unroll
  for (int j = 0; j < 4; ++j) {
    float4 a = d4[j * 64 + lane], w = w4[j * 64 + lane];
    s += a.x * w.x + a.y * w.y + a.z * w.z + a.w * w.w;
  }
#pragma unroll
  for (int off = 32; off; off >>= 1) s += __shfl_xor(s, off);
  if (lane == 0) Qb[wid] = s + bq[h * DK + k];
}

// ---------- fused e kernel ----------
// 256 threads, 4 waves; block = (h, b, t0(64 rows), colhalf(256 k-cols)).
// 9-tile pipeline (8 enc tiles BK=128 + conv tile), XOR-swizzled LDS dbuf,
// depth-4 B register prefetch with fully static indexing. Partial e summed in softmax.
__global__ __launch_bounds__(256) void e_kernel(const short* __restrict__ encb,
                                                const short* __restrict__ Bp,
                                                const float* __restrict__ S,
                                                const float* __restrict__ Qb,
                                                const float* __restrict__ gw,
                                                const int* __restrict__ lens,
                                                float* __restrict__ ebuf2) {
  __shared__ short At[2][64 * 128];
  __shared__ float epart[4][64];

  int bid = blockIdx.x;                 // 4096 = h(4) x b(16) x t0(32) x ch(2)
  int ch = bid & 1;
  int t0 = ((bid >> 1) & 31) << 6;
  int b  = (bid >> 6) & 15;
  int h  = bid >> 10;
  int tid = threadIdx.x; int w = tid >> 6; int l = tid & 63;
  int lrow = l & 15, lhi = l >> 4;
  int len = lens[b];
  float invlen = 1.0f / (float)len;
  int af = (100 * (h + 1)) >> 2;

  const short* encB = encb + ((size_t)(b * TT + t0)) * EPROJS;
  // B base: lane-constant part; per-step uniform bump of bi*16384 shorts
  const short* pbase = Bp + (size_t)h * 589824 + ch * 8192 + w * 2048 + l * 8;

  // staging geometry: thread covers row srow, logical chunks sc4..sc4+3
  int srow = tid >> 2;
  int sc4 = (tid & 3) * 4;
  const short* sbase = encB + (size_t)srow * EPROJS + sc4 * 8;
  int wo0 = srow * 128 + (((sc4 + 0) ^ (srow & 7)) << 3);
  int wo1 = srow * 128 + (((sc4 + 1) ^ (srow & 7)) << 3);
  int wo2 = srow * 128 + (((sc4 + 2) ^ (srow & 7)) << 3);
  int wo3 = srow * 128 + (((sc4 + 3) ^ (srow & 7)) << 3);
  int rx = lrow & 7;

  // prolog: B depth-4 prefetch (bi = 0..3) + tile-0 staging loads
  bf16x8 Bq[4][4];
#pragma unroll
  for (int kk = 0; kk < 4; ++kk)
#pragma unroll
    for (int n = 0; n < 4; ++n)
      Bq[kk][n] = *reinterpret_cast<const bf16x8*>(pbase + kk * 16384 + n * 512);

  bf16x8 s0 = *reinterpret_cast<const bf16x8*>(sbase);
  bf16x8 s1 = *reinterpret_cast<const bf16x8*>(sbase + 8);
  bf16x8 s2 = *reinterpret_cast<const bf16x8*>(sbase + 16);
  bf16x8 s3 = *reinterpret_cast<const bf16x8*>(sbase + 24);

  f32x4 acc[4][4] = {};

  // write tile 0 into At[0]
  *reinterpret_cast<bf16x8*>(&At[0][wo0]) = s0;
  *reinterpret_cast<bf16x8*>(&At[0][wo1]) = s1;
  *reinterpret_cast<bf16x8*>(&At[0][wo2]) = s2;
  *reinterpret_cast<bf16x8*>(&At[0][wo3]) = s3;

  const float* Sh = S + h * 202 * 128;

#pragma unroll
  for (int tl = 0; tl < 9; ++tl) {
    // stage source for tile tl+1
    if (tl < 7) {
      const short* sp = sbase + (tl + 1) * 128;
      s0 = *reinterpret_cast<const bf16x8*>(sp);
      s1 = *reinterpret_cast<const bf16x8*>(sp + 8);
      s2 = *reinterpret_cast<const bf16x8*>(sp + 16);
      s3 = *reinterpret_cast<const bf16x8*>(sp + 24);
    } else if (tl == 7) {
      // conv tile: v[c] = (Sh[hi+1][c]-Sh[lo][c])*invlen for this thread's row
      int t = t0 + srow;
      int lo = af - t; if (lo < 0) lo = 0;
      int hi = af - t + len - 1; if (hi > 2 * af) hi = 2 * af;
      bool any = (hi >= lo);
      const float* Plo = Sh + lo * 128;
      const float* Phi = Sh + (hi + 1) * 128;
#pragma unroll
      for (int j = 0; j < 4; ++j) {
        short o[8];
#pragma unroll
        for (int e = 0; e < 8; ++e) {
          int c = (sc4 + j) * 8 + e;
          float v = any ? (Phi[c] - Plo[c]) * invlen : 0.f;
          o[e] = f2bf(v);
        }
        bf16x8 pk = *reinterpret_cast<bf16x8*>(o);
        if (j == 0) s0 = pk; else if (j == 1) s1 = pk; else if (j == 2) s2 = pk; else s3 = pk;
      }
    }
    __syncthreads();
#pragma unroll
    for (int kk = 0; kk < 4; ++kk) {
      bf16x8 afr[4];
      int x = ((kk * 4 + lhi) ^ rx) << 3;
#pragma unroll
      for (int m = 0; m < 4; ++m)
        afr[m] = *reinterpret_cast<const bf16x8*>(&At[tl & 1][(m * 16 + lrow) * 128 + x]);
#pragma unroll
      for (int m = 0; m < 4; ++m)
#pragma unroll
        for (int n = 0; n < 4; ++n)
          acc[m][n] = __builtin_amdgcn_mfma_f32_16x16x32_bf16(afr[m], Bq[kk][n], acc[m][n], 0, 0, 0);
      int bi = tl * 4 + kk + 4;
      if (bi < 36) {
        const short* bp = pbase + (size_t)bi * 16384;
#pragma unroll
        for (int n = 0; n < 4; ++n)
          Bq[kk][n] = *reinterpret_cast<const bf16x8*>(bp + n * 512);
      }
    }
    if (tl < 8) {
      int nb = (tl + 1) & 1;
      *reinterpret_cast<bf16x8*>(&At[nb][wo0]) = s0;
      *reinterpret_cast<bf16x8*>(&At[nb][wo1]) = s1;
      *reinterpret_cast<bf16x8*>(&At[nb][wo2]) = s2;
      *reinterpret_cast<bf16x8*>(&At[nb][wo3]) = s3;
    }
  }

  // epilogue: tanh(pre + Q) * g_w, reduce over k (this block's 256 cols)
  float part[4][4];
#pragma unroll
  for (int m = 0; m < 4; ++m)
#pragma unroll
    for (int r = 0; r < 4; ++r) part[m][r] = 0.f;

#pragma unroll
  for (int n = 0; n < 4; ++n) {
    int col = ch * 256 + w * 64 + n * 16 + lrow;
    float q = Qb[(h * BB + b) * DK + col];
    float g = gw[h * DK + col];
#pragma unroll
    for (int m = 0; m < 4; ++m)
#pragma unroll
      for (int r = 0; r < 4; ++r)
        part[m][r] += fast_tanh(acc[m][n][r] + q) * g;
  }
#pragma unroll
  for (int off = 1; off < 16; off <<= 1)
#pragma unroll
    for (int m = 0; m < 4; ++m)
#pragma unroll
      for (int r = 0; r < 4; ++r) part[m][r] += __shfl_xor(part[m][r], off);

  if (lrow == 0) {
#pragma unroll
    for (int m = 0; m < 4; ++m)
#pragma unroll
      for (int r = 0; r < 4; ++r) epart[w][m * 16 + lhi * 4 + r] = part[m][r];
  }
  __syncthreads();
  if (tid < 64) {
    float s = 0.f;
#pragma unroll
    for (int ww = 0; ww < 4; ++ww) s += epart[ww][tid];
    ebuf2[(size_t)((ch * 64) + h * BB + b) * TT + t0 + tid] = s;
  }
}

// ---------- masked softmax over t (sums the two col-half partials) ----------
__global__ __launch_bounds__(256) void softmax_kernel(const float* __restrict__ ebuf2,
                                                      const int* __restrict__ lens,
                                                      float* __restrict__ wout) {
  int hb = blockIdx.x; int b = hb & (BB - 1);
  int tid = threadIdx.x;
  int len = lens[b];
  const float scaling = 0.04419417382415922f;  // 1/sqrt(512)
  const float* e0 = ebuf2 + (size_t)hb * TT;
  const float* e1 = ebuf2 + (size_t)(64 + hb) * TT;
  float vals[8];
  float mx = -1e30f;
#pragma unroll
  for (int j = 0; j < 8; ++j) {
    int t = j * 256 + tid;
    float v = (t < len) ? scaling * (e0[t] + e1[t]) : -1e30f;
    vals[j] = v; mx = fmaxf(mx, v);
  }
  __shared__ float red[256];
  red[tid] = mx; __syncthreads();
  for (int s2 = 128; s2; s2 >>= 1) { if (tid < s2) red[tid] = fmaxf(red[tid], red[tid + s2]); __syncthreads(); }
  mx = red[0]; __syncthreads();
  float sum = 0.f;
#pragma unroll
  for (int j = 0; j < 8; ++j) {
    int t = j * 256 + tid;
    vals[j] = (t < len) ? __expf(vals[j] - mx) : 0.f;
    sum += vals[j];
  }
  red[tid] = sum; __syncthreads();
  for (int s2 = 128; s2; s2 >>= 1) { if (tid < s2) red[tid] += red[tid + s2]; __syncthreads(); }
  float inv = 1.f / red[0];
#pragma unroll
  for (int j = 0; j < 8; ++j)
    wout[(size_t)hb * TT + j * 256 + tid] = vals[j] * inv;
}

__global__ __launch_bounds__(256) void zero_kernel(float* __restrict__ p, int n) {
  int i = blockIdx.x * blockDim.x + threadIdx.x;
  if (i < n) p[i] = 0.f;
}

// ---------- ctx[h][b][e] = sum_t w[h][b][t] * enc_bf16[b][t][e] ----------
__global__ __launch_bounds__(256) void ctx_kernel(const short* __restrict__ encb,
                                                  const float* __restrict__ wout,
                                                  float* __restrict__ ctx) {
  int bid = blockIdx.x;                      // 16 * 4 * 8 = 512
  int tc = bid & 7; int ec = (bid >> 3) & 3; int b = bid >> 5;
  int tid = threadIdx.x;
  int ecol = ec * 256 + tid;
  int t0 = tc * 256;
  __shared__ float wls[4][256];
#pragma unroll
  for (int h = 0; h < 4; ++h) wls[h][tid] = wout[(size_t)(h * BB + b) * TT + t0 + tid];
  __syncthreads();
  float a0 = 0.f, a1 = 0.f, a2 = 0.f, a3 = 0.f;
  const short* ep = encb + ((size_t)(b * TT + t0)) * EPROJS + ecol;
  for (int t2 = 0; t2 < 256; ++t2) {
    float v = bf2f(ep[(size_t)t2 * EPROJS]);
    a0 += wls[0][t2] * v; a1 += wls[1][t2] * v; a2 += wls[2][t2] * v; a3 += wls[3][t2] * v;
  }
  atomicAdd(&ctx[(0 * BB + b) * EPROJS + ecol], a0);
  atomicAdd(&ctx[(1 * BB + b) * EPROJS + ecol], a1);
  atomicAdd(&ctx[(2 * BB + b) * EPROJS + ecol], a2);
  atomicAdd(&ctx[(3 * BB + b) * EPROJS + ecol], a3);
}

// ---------- cv[b][h*512+v] = ctx[h][b] . Wv[h][v] ; one wave per (h,v), all 16 b ----------
__global__ __launch_bounds__(256) void cv_kernel(const float* __restrict__ ctx,
                                                 const float* __restrict__ Wv,
                                                 float* __restrict__ cvb) {
  int wid = (blockIdx.x * blockDim.x + threadIdx.x) >> 6;   // 0..2047
  int lane = threadIdx.x & 63;
  int v = wid & (DV - 1); int h = wid >> 9;
  const float4* w4 = reinterpret_cast<const float4*>(Wv + (size_t)(h * DV + v) * EPROJS);
  float acc[BB];
#pragma unroll
  for (int b = 0; b < BB; ++b) acc[b] = 0.f;
#pragma unroll
  for (int j = 0; j < 4; ++j) {
    float4 ww = w4[j * 64 + lane];
#pragma unroll
    for (int b = 0; b < BB; ++b) {
      float4 a = reinterpret_cast<const float4*>(ctx + (size_t)(h * BB + b) * EPROJS)[j * 64 + lane];
      acc[b] += a.x * ww.x + a.y * ww.y + a.z * ww.z + a.w * ww.w;
    }
  }
#pragma unroll
  for (int off = 32; off; off >>= 1)
#pragma unroll
    for (int b = 0; b < BB; ++b) acc[b] += __shfl_xor(acc[b], off);
  if (lane == 0) {
#pragma unroll
    for (int b = 0; b < BB; ++b) cvb[b * 2048 + h * DV + v] = acc[b];
  }
}

// ---------- c[b][p] = cv[b] . Wo[p] ; one wave per p, all 16 b ----------
__global__ __launch_bounds__(256) void out_kernel(const float* __restrict__ cvb,
                                                  const float* __restrict__ Wo,
                                                  float* __restrict__ outc) {
  int p = (blockIdx.x * blockDim.x + threadIdx.x) >> 6;   // 0..1023
  int lane = threadIdx.x & 63;
  const float4* w4 = reinterpret_cast<const float4*>(Wo + (size_t)p * 2048);
  float acc[BB];
#pragma unroll
  for (int b = 0; b < BB; ++b) acc[b] = 0.f;
#pragma unroll
  for (int j = 0; j < 8; ++j) {
    float4 ww = w4[j * 64 + lane];
#pragma unroll
    for (int b = 0; b < BB; ++b) {
      float4 a = reinterpret_cast<const float4*>(cvb + (size_t)b * 2048)[j * 64 + lane];
      acc[b] += a.x * ww.x + a.y * ww.y + a.z * ww.z + a.w * ww.w;
    }
  }
#pragma unroll
  for (int off = 32; off; off >>= 1)
#pragma unroll
    for (int b = 0; b < BB; ++b) acc[b] += __shfl_xor(acc[b], off);
  if (lane == 0) {
#pragma unroll
    for (int b = 0; b < BB; ++b) outc[b * 1024 + p] = acc[b];
  }
}

extern "C" void kernel_launch(void* const* d_in, const int* in_sizes, int n_in,
                              void* d_out, int out_size, void* d_ws, size_t ws_size,
                              hipStream_t stream) {
  const float* enc  = (const float*)d_in[0];
  const int*   lens = (const int*)d_in[1];
  const float* dec  = (const float*)d_in[2];
  const float* Wq   = (const float*)d_in[3];
  const float* bq   = (const float*)d_in[4];
  const float* Wk   = (const float*)d_in[5];
  const float* Wv   = (const float*)d_in[6];
  const float* gw   = (const float*)d_in[7];
  const float* Watt = (const float*)d_in[9];
  const float* cw0  = (const float*)d_in[10];
  const float* cw1  = (const float*)d_in[11];
  const float* cw2  = (const float*)d_in[12];
  const float* cw3  = (const float*)d_in[13];
  const float* Wo   = (const float*)d_in[14];
  float* out = (float*)d_out;

  char* ws = (char*)d_ws;
  short* Bp    = (short*)(ws);                 // 4,718,592 B
  float* S     = (float*)(ws + 4718592);       // 413,696 B
  float* Qb    = (float*)(ws + 5132288);       // 131,072 B
  float* ebuf2 = (float*)(ws + 5263360);       // 1,048,576 B (2 col-half partials)
  float* ctx   = (float*)(ws + 6311936);       // 262,144 B
  float* cvb   = (float*)(ws + 6574080);       // 131,072 B
  short* encb  = (short*)(ws + 6815744);       // 67,108,864 B

  float* wsout = out + 16384;                  // ws output region (4,16,2048)

  cvt_kernel<<<32768, 256, 0, stream>>>(enc, encb, 8388608);
  packB_kernel<<<1152, 256, 0, stream>>>(Wk, Watt, Bp);
  prefix_kernel<<<4, 128, 0, stream>>>(cw0, cw1, cw2, cw3, S);
  q_kernel<<<8192, 256, 0, stream>>>(dec, Wq, bq, Qb);
  zero_kernel<<<256, 256, 0, stream>>>(ctx, 65536);
  e_kernel<<<4096, 256, 0, stream>>>(encb, Bp, S, Qb, gw, lens, ebuf2);
  softmax_kernel<<<64, 256, 0, stream>>>(ebuf2, lens, wsout);
  ctx_kernel<<<512, 256, 0, stream>>>(encb, wsout, ctx);
  cv_kernel<<<512, 256, 0, stream>>>(ctx, Wv, cvb);
  out_kernel<<<256, 256, 0, stream>>>(cvb, Wo, out);
}

// Round 5
// 364.040 us; speedup vs baseline: 1.1465x; 1.1465x over previous
//
#include <hip/hip_runtime.h>

#define EPROJS 1024
#define DUNITS 1024
#define AHEADS 4
#define DK 512
#define DV 512
#define CCH 128
#define BB 16
#define TT 2048

typedef __attribute__((ext_vector_type(8))) short bf16x8;
typedef __attribute__((ext_vector_type(4))) float f32x4;

static __device__ __forceinline__ short f2bf(float x) {
  unsigned u = __float_as_uint(x);
  unsigned r = u + 0x7fffu + ((u >> 16) & 1u);   // RNE to bf16 (inputs finite)
  return (short)(r >> 16);
}
static __device__ __forceinline__ float bf2f(short x) {
  return __uint_as_float(((unsigned)(unsigned short)x) << 16);
}

static __device__ __forceinline__ float fast_tanh(float x) {
  float e2 = __expf(2.0f * x);
  return 1.0f - 2.0f / (e2 + 1.0f);
}

// ---------- f32 -> bf16 conversion (vector of 4) ----------
__global__ __launch_bounds__(256) void cvt_kernel(const float* __restrict__ in,
                                                  short* __restrict__ out, int n4) {
  int i = blockIdx.x * blockDim.x + threadIdx.x;
  if (i >= n4) return;
  float4 v = reinterpret_cast<const float4*>(in)[i];
  short4 o;
  o.x = f2bf(v.x); o.y = f2bf(v.y); o.z = f2bf(v.z); o.w = f2bf(v.w);
  reinterpret_cast<short4*>(out)[i] = o;
}

// ---------- pack B = [Wk | Watt] into MFMA fragment order ----------
// Bp[h][kkidx(36)][nblk(32)][lane(64)][8]; kkidx<32 -> Wk (k=kkidx*32), else Watt.
__global__ __launch_bounds__(256) void packB_kernel(const float* __restrict__ Wk,
                                                    const float* __restrict__ Watt,
                                                    short* __restrict__ Bp) {
  int idx = blockIdx.x * 256 + threadIdx.x;          // 4*36*32*64 = 294912
  if (idx >= 294912) return;
  int lane = idx & 63; int t = idx >> 6;
  int nblk = t & 31; t >>= 5;
  int kkidx = t % 36; int h = t / 36;
  int col = nblk * 16 + (lane & 15);
  int k0 = kkidx * 32 + (lane >> 4) * 8;
  const float* src;
  if (k0 < 1024) src = Wk + ((size_t)(h * DK + col)) * EPROJS + k0;
  else           src = Watt + ((size_t)(h * DK + col)) * CCH + (k0 - 1024);
  float4 v0 = reinterpret_cast<const float4*>(src)[0];
  float4 v1 = reinterpret_cast<const float4*>(src)[1];
  short o[8] = { f2bf(v0.x), f2bf(v0.y), f2bf(v0.z), f2bf(v0.w),
                 f2bf(v1.x), f2bf(v1.y), f2bf(v1.z), f2bf(v1.w) };
  *reinterpret_cast<bf16x8*>(Bp + (size_t)idx * 8) = *reinterpret_cast<bf16x8*>(o);
}

// ---------- filter prefix sums: S[h][tau][c], tau in [0, L] ----------
__global__ __launch_bounds__(128) void prefix_kernel(const float* __restrict__ w0,
                                                     const float* __restrict__ w1,
                                                     const float* __restrict__ w2,
                                                     const float* __restrict__ w3,
                                                     float* __restrict__ S) {
  int h = blockIdx.x, c = threadIdx.x;
  const float* wk = (h == 0) ? w0 : (h == 1) ? w1 : (h == 2) ? w2 : w3;
  int af = (100 * (h + 1)) >> 2;
  int L = 2 * af + 1;
  float* Sh = S + h * 202 * 128;
  float s = 0.f;
  Sh[c] = 0.f;
  for (int t = 0; t < L; ++t) { s += wk[c * L + t]; Sh[(t + 1) * 128 + c] = s; }
}

// ---------- Q[h][b][k] ----------
__global__ __launch_bounds__(256) void q_kernel(const float* __restrict__ dec,
                                                const float* __restrict__ Wq,
                                                const float* __restrict__ bq,
                                                float* __restrict__ Qb) {
  int wid = (blockIdx.x * blockDim.x + threadIdx.x) >> 6;
  int lane = threadIdx.x & 63;
  int k = wid & (DK - 1); int hb = wid >> 9; int b = hb & (BB - 1); int h = hb >> 4;
  const float4* d4 = reinterpret_cast<const float4*>(dec + b * DUNITS);
  const float4* w4 = reinterpret_cast<const float4*>(Wq + (size_t)(h * DK + k) * DUNITS);
  float s = 0.f;
#pragma unroll
  for (int j = 0; j < 4; ++j) {
    float4 a = d4[j * 64 + lane], w = w4[j * 64 + lane];
    s += a.x * w.x + a.y * w.y + a.z * w.z + a.w * w.w;
  }
#pragma unroll
  for (int off = 32; off; off >>= 1) s += __shfl_xor(s, off);
  if (lane == 0) Qb[wid] = s + bq[h * DK + k];
}

// ---------- fused e kernel ----------
// Round-3 structure (512 thr, 8 waves, full 512 cols, BK=128 dbuf, depth-1 B prefetch)
// + XCD-grouped swizzle: the 4 heads of one (b,t0) enc tile sit in adjacent per-XCD
//   slots -> 3 of 4 A-tile reads become L2 hits.
// + conv folded in as pipeline tile 8 (kkidx 32..35); g_b dropped (softmax shift-inv).
__global__ __launch_bounds__(512, 3) void e_kernel(const short* __restrict__ encb,
                                                   const short* __restrict__ Bp,
                                                   const float* __restrict__ S,
                                                   const float* __restrict__ Qb,
                                                   const float* __restrict__ gw,
                                                   const int* __restrict__ lens,
                                                   float* __restrict__ ebuf) {
  __shared__ short At[2][64 * 128];
  __shared__ float epart[8][64];

  // decode: bid = xcd + 8*(gq*4 + h), group g = xcd + 8*gq = (b, t0)
  int bid = blockIdx.x;
  int xcd = bid & 7; int q = bid >> 3;
  int h = q & 3; int gq = q >> 2;          // gq in [0,64)
  int g = xcd + (gq << 3);                 // g in [0,512)
  int b = g >> 5; int t0 = (g & 31) << 6;

  int tid = threadIdx.x; int w = tid >> 6; int l = tid & 63;
  int lrow = l & 15, lhi = l >> 4;
  int len = lens[b];
  float invlen = 1.0f / (float)len;
  int af = (100 * (h + 1)) >> 2;

  const short* encB = encb + ((size_t)(b * TT + t0)) * EPROJS;
  const short* BpH = Bp + (size_t)h * 589824;

  // staging: thread covers row srow, chunks sc and sc+8
  int srow = tid >> 3;
  int sc = tid & 7;
  int wo0 = srow * 128 + ((sc ^ (srow & 7)) << 3);
  int wo1 = srow * 128 + (((sc + 8) ^ (srow & 7)) << 3);
  const short* sbase = encB + (size_t)srow * EPROJS + sc * 8;
  int rx = lrow & 7;

  // B depth-1 prefetch: kkidx 0
  bf16x8 bnext[4];
#pragma unroll
  for (int n = 0; n < 4; ++n)
    bnext[n] = *reinterpret_cast<const bf16x8*>(BpH + (w * 4 + n) * 512 + l * 8);

  // tile-0 staging loads + write into At[0]
  bf16x8 s0 = *reinterpret_cast<const bf16x8*>(sbase);
  bf16x8 s1 = *reinterpret_cast<const bf16x8*>(sbase + 64);

  f32x4 acc[4][4] = {};

  *reinterpret_cast<bf16x8*>(&At[0][wo0]) = s0;
  *reinterpret_cast<bf16x8*>(&At[0][wo1]) = s1;

  const float* Sh = S + h * 202 * 128;

  // 9-tile pipeline: tiles 0..7 = enc (kkidx 0..31), tile 8 = conv (kkidx 32..35)
  for (int tl = 0; tl < 9; ++tl) {
    if (tl < 7) {
      s0 = *reinterpret_cast<const bf16x8*>(sbase + (tl + 1) * 128);
      s1 = *reinterpret_cast<const bf16x8*>(sbase + (tl + 1) * 128 + 64);
    } else if (tl == 7) {
      // conv tile values for this thread's row/chunks
      int t = t0 + srow;
      int lo = af - t; if (lo < 0) lo = 0;
      int hi = af - t + len - 1; if (hi > 2 * af) hi = 2 * af;
      bool any = (hi >= lo);
      const float* Plo = Sh + lo * 128;
      const float* Phi = Sh + (hi + 1) * 128;
      short o0[8], o1[8];
#pragma unroll
      for (int e = 0; e < 8; ++e) {
        int c = sc * 8 + e;
        float v0 = any ? (Phi[c] - Plo[c]) * invlen : 0.f;
        float v1 = any ? (Phi[c + 64] - Plo[c + 64]) * invlen : 0.f;
        o0[e] = f2bf(v0); o1[e] = f2bf(v1);
      }
      s0 = *reinterpret_cast<bf16x8*>(o0);
      s1 = *reinterpret_cast<bf16x8*>(o1);
    }
    __syncthreads();
#pragma unroll
    for (int kk = 0; kk < 4; ++kk) {
      bf16x8 bcur[4];
#pragma unroll
      for (int n = 0; n < 4; ++n) bcur[n] = bnext[n];
      int nk = tl * 4 + kk + 1;
      if (nk < 36) {
        const short* bp = BpH + (size_t)nk * 16384 + l * 8;
#pragma unroll
        for (int n = 0; n < 4; ++n)
          bnext[n] = *reinterpret_cast<const bf16x8*>(bp + (w * 4 + n) * 512);
      }
      bf16x8 afr[4];
      int x = ((kk * 4 + lhi) ^ rx) << 3;
#pragma unroll
      for (int m = 0; m < 4; ++m)
        afr[m] = *reinterpret_cast<const bf16x8*>(&At[tl & 1][(m * 16 + lrow) * 128 + x]);
#pragma unroll
      for (int m = 0; m < 4; ++m)
#pragma unroll
        for (int n = 0; n < 4; ++n)
          acc[m][n] = __builtin_amdgcn_mfma_f32_16x16x32_bf16(afr[m], bcur[n], acc[m][n], 0, 0, 0);
    }
    if (tl < 8) {
      int nb = (tl + 1) & 1;
      *reinterpret_cast<bf16x8*>(&At[nb][wo0]) = s0;
      *reinterpret_cast<bf16x8*>(&At[nb][wo1]) = s1;
    }
  }

  // epilogue: tanh(pre + Q) * g_w, reduce over k (g_b dropped: softmax shift-invariant)
  float part[4][4];
#pragma unroll
  for (int m = 0; m < 4; ++m)
#pragma unroll
    for (int r = 0; r < 4; ++r) part[m][r] = 0.f;

#pragma unroll
  for (int n = 0; n < 4; ++n) {
    int col = w * 64 + n * 16 + lrow;
    float qv = Qb[(h * BB + b) * DK + col];
    float gv = gw[h * DK + col];
#pragma unroll
    for (int m = 0; m < 4; ++m)
#pragma unroll
      for (int r = 0; r < 4; ++r)
        part[m][r] += fast_tanh(acc[m][n][r] + qv) * gv;
  }
#pragma unroll
  for (int off = 1; off < 16; off <<= 1)
#pragma unroll
    for (int m = 0; m < 4; ++m)
#pragma unroll
      for (int r = 0; r < 4; ++r) part[m][r] += __shfl_xor(part[m][r], off);

  if (lrow == 0) {
#pragma unroll
    for (int m = 0; m < 4; ++m)
#pragma unroll
      for (int r = 0; r < 4; ++r) epart[w][m * 16 + lhi * 4 + r] = part[m][r];
  }
  __syncthreads();
  if (tid < 64) {
    float s = 0.f;
#pragma unroll
    for (int ww = 0; ww < 8; ++ww) s += epart[ww][tid];
    ebuf[(size_t)(h * BB + b) * TT + t0 + tid] = s;
  }
}

// ---------- masked softmax over t; writes ws region of d_out ----------
__global__ __launch_bounds__(256) void softmax_kernel(const float* __restrict__ ebuf,
                                                      const int* __restrict__ lens,
                                                      float* __restrict__ wout) {
  int hb = blockIdx.x; int b = hb & (BB - 1);
  int tid = threadIdx.x;
  int len = lens[b];
  const float scaling = 0.04419417382415922f;  // 1/sqrt(512)
  const float* er = ebuf + (size_t)hb * TT;
  float vals[8];
  float mx = -1e30f;
#pragma unroll
  for (int j = 0; j < 8; ++j) {
    int t = j * 256 + tid;
    float v = (t < len) ? scaling * er[t] : -1e30f;
    vals[j] = v; mx = fmaxf(mx, v);
  }
  __shared__ float red[256];
  red[tid] = mx; __syncthreads();
  for (int s2 = 128; s2; s2 >>= 1) { if (tid < s2) red[tid] = fmaxf(red[tid], red[tid + s2]); __syncthreads(); }
  mx = red[0]; __syncthreads();
  float sum = 0.f;
#pragma unroll
  for (int j = 0; j < 8; ++j) {
    int t = j * 256 + tid;
    vals[j] = (t < len) ? __expf(vals[j] - mx) : 0.f;
    sum += vals[j];
  }
  red[tid] = sum; __syncthreads();
  for (int s2 = 128; s2; s2 >>= 1) { if (tid < s2) red[tid] += red[tid + s2]; __syncthreads(); }
  float inv = 1.f / red[0];
#pragma unroll
  for (int j = 0; j < 8; ++j)
    wout[(size_t)hb * TT + j * 256 + tid] = vals[j] * inv;
}

__global__ __launch_bounds__(256) void zero_kernel(float* __restrict__ p, int n) {
  int i = blockIdx.x * blockDim.x + threadIdx.x;
  if (i < n) p[i] = 0.f;
}

// ---------- ctx[h][b][e] = sum_t w[h][b][t] * enc_bf16[b][t][e] ----------
__global__ __launch_bounds__(256) void ctx_kernel(const short* __restrict__ encb,
                                                  const float* __restrict__ wout,
                                                  float* __restrict__ ctx) {
  int bid = blockIdx.x;                      // 16 * 4 * 8 = 512
  int tc = bid & 7; int ec = (bid >> 3) & 3; int b = bid >> 5;
  int tid = threadIdx.x;
  int ecol = ec * 256 + tid;
  int t0 = tc * 256;
  __shared__ float wls[4][256];
#pragma unroll
  for (int h = 0; h < 4; ++h) wls[h][tid] = wout[(size_t)(h * BB + b) * TT + t0 + tid];
  __syncthreads();
  float a0 = 0.f, a1 = 0.f, a2 = 0.f, a3 = 0.f;
  const short* ep = encb + ((size_t)(b * TT + t0)) * EPROJS + ecol;
  for (int t2 = 0; t2 < 256; ++t2) {
    float v = bf2f(ep[(size_t)t2 * EPROJS]);
    a0 += wls[0][t2] * v; a1 += wls[1][t2] * v; a2 += wls[2][t2] * v; a3 += wls[3][t2] * v;
  }
  atomicAdd(&ctx[(0 * BB + b) * EPROJS + ecol], a0);
  atomicAdd(&ctx[(1 * BB + b) * EPROJS + ecol], a1);
  atomicAdd(&ctx[(2 * BB + b) * EPROJS + ecol], a2);
  atomicAdd(&ctx[(3 * BB + b) * EPROJS + ecol], a3);
}

// ---------- cv[b][h*512+v] = ctx[h][b] . Wv[h][v] ; one wave per (h,v), all 16 b ----------
__global__ __launch_bounds__(256) void cv_kernel(const float* __restrict__ ctx,
                                                 const float* __restrict__ Wv,
                                                 float* __restrict__ cvb) {
  int wid = (blockIdx.x * blockDim.x + threadIdx.x) >> 6;   // 0..2047
  int lane = threadIdx.x & 63;
  int v = wid & (DV - 1); int h = wid >> 9;
  const float4* w4 = reinterpret_cast<const float4*>(Wv + (size_t)(h * DV + v) * EPROJS);
  float acc[BB];
#pragma unroll
  for (int b = 0; b < BB; ++b) acc[b] = 0.f;
#pragma unroll
  for (int j = 0; j < 4; ++j) {
    float4 ww = w4[j * 64 + lane];
#pragma unroll
    for (int b = 0; b < BB; ++b) {
      float4 a = reinterpret_cast<const float4*>(ctx + (size_t)(h * BB + b) * EPROJS)[j * 64 + lane];
      acc[b] += a.x * ww.x + a.y * ww.y + a.z * ww.z + a.w * ww.w;
    }
  }
#pragma unroll
  for (int off = 32; off; off >>= 1)
#pragma unroll
    for (int b = 0; b < BB; ++b) acc[b] += __shfl_xor(acc[b], off);
  if (lane == 0) {
#pragma unroll
    for (int b = 0; b < BB; ++b) cvb[b * 2048 + h * DV + v] = acc[b];
  }
}

// ---------- c[b][p] = cv[b] . Wo[p] ; one wave per p, all 16 b ----------
__global__ __launch_bounds__(256) void out_kernel(const float* __restrict__ cvb,
                                                  const float* __restrict__ Wo,
                                                  float* __restrict__ outc) {
  int p = (blockIdx.x * blockDim.x + threadIdx.x) >> 6;   // 0..1023
  int lane = threadIdx.x & 63;
  const float4* w4 = reinterpret_cast<const float4*>(Wo + (size_t)p * 2048);
  float acc[BB];
#pragma unroll
  for (int b = 0; b < BB; ++b) acc[b] = 0.f;
#pragma unroll
  for (int j = 0; j < 8; ++j) {
    float4 ww = w4[j * 64 + lane];
#pragma unroll
    for (int b = 0; b < BB; ++b) {
      float4 a = reinterpret_cast<const float4*>(cvb + (size_t)b * 2048)[j * 64 + lane];
      acc[b] += a.x * ww.x + a.y * ww.y + a.z * ww.z + a.w * ww.w;
    }
  }
#pragma unroll
  for (int off = 32; off; off >>= 1)
#pragma unroll
    for (int b = 0; b < BB; ++b) acc[b] += __shfl_xor(acc[b], off);
  if (lane == 0) {
#pragma unroll
    for (int b = 0; b < BB; ++b) outc[b * 1024 + p] = acc[b];
  }
}

extern "C" void kernel_launch(void* const* d_in, const int* in_sizes, int n_in,
                              void* d_out, int out_size, void* d_ws, size_t ws_size,
                              hipStream_t stream) {
  const float* enc  = (const float*)d_in[0];
  const int*   lens = (const int*)d_in[1];
  const float* dec  = (const float*)d_in[2];
  const float* Wq   = (const float*)d_in[3];
  const float* bq   = (const float*)d_in[4];
  const float* Wk   = (const float*)d_in[5];
  const float* Wv   = (const float*)d_in[6];
  const float* gw   = (const float*)d_in[7];
  const float* Watt = (const float*)d_in[9];
  const float* cw0  = (const float*)d_in[10];
  const float* cw1  = (const float*)d_in[11];
  const float* cw2  = (const float*)d_in[12];
  const float* cw3  = (const float*)d_in[13];
  const float* Wo   = (const float*)d_in[14];
  float* out = (float*)d_out;

  char* ws = (char*)d_ws;
  short* Bp    = (short*)(ws);                 // 4,718,592 B
  float* S     = (float*)(ws + 4718592);       // 413,696 B
  float* Qb    = (float*)(ws + 5132288);       // 131,072 B
  float* ebuf  = (float*)(ws + 5263360);       // 524,288 B
  float* ctx   = (float*)(ws + 6311936);       // 262,144 B
  float* cvb   = (float*)(ws + 6574080);       // 131,072 B
  short* encb  = (short*)(ws + 6815744);       // 67,108,864 B

  float* wsout = out + 16384;                  // ws output region (4,16,2048)

  cvt_kernel<<<32768, 256, 0, stream>>>(enc, encb, 8388608);
  packB_kernel<<<1152, 256, 0, stream>>>(Wk, Watt, Bp);
  prefix_kernel<<<4, 128, 0, stream>>>(cw0, cw1, cw2, cw3, S);
  q_kernel<<<8192, 256, 0, stream>>>(dec, Wq, bq, Qb);
  zero_kernel<<<256, 256, 0, stream>>>(ctx, 65536);
  e_kernel<<<2048, 512, 0, stream>>>(encb, Bp, S, Qb, gw, lens, ebuf);
  softmax_kernel<<<64, 256, 0, stream>>>(ebuf, lens, wsout);
  ctx_kernel<<<512, 256, 0, stream>>>(encb, wsout, ctx);
  cv_kernel<<<512, 256, 0, stream>>>(ctx, Wv, cvb);
  out_kernel<<<256, 256, 0, stream>>>(cvb, Wo, out);
}